// Round 5
// baseline (777.423 us; speedup 1.0000x reference)
//
#include <hip/hip_runtime.h>

// UniversalSAE: z = TopK32((x - pre_bias) @ enc_w.T), rec_i = z @ dec_w_i.T + post_bias_i
// R5: R4 with NT-store type fix (ext_vector f32x4 instead of HIP float4 struct).
// Compile-time D via template<SRC> dual-launch (device-guarded) +
// seeded 1-barrier-per-iter bisect + ushort4-vectorized decode + NT stores.

#define BATCH  16384
#define HIDDEN 8192
#define DIM0   512
#define DIM1   768
#define TOPK   32
#define CAND_MAX 256
#define WIN_LO 40
#define WIN_HI 96

// probe seeds: fkey16(bf16(0.4)) and fkey16(bf16(2.5)); correctness independent of values
#define KLO_G 0xBECDu
#define KHI_G 0xC020u

typedef __attribute__((ext_vector_type(8))) short bf16x8;
typedef __attribute__((ext_vector_type(8))) unsigned short u16x8;
typedef __attribute__((ext_vector_type(4))) float f32x4;

__device__ __forceinline__ unsigned fkey(float f) {
    unsigned u = __float_as_uint(f);
    return (u & 0x80000000u) ? ~u : (u | 0x80000000u);
}
__device__ __forceinline__ unsigned fkey16(unsigned short h) {
    return (h & 0x8000u) ? (unsigned)((~h) & 0xFFFFu) : (unsigned)(h | 0x8000u);
}
__device__ __forceinline__ unsigned short f2b(float f) {  // fp32 -> bf16 RNE
    unsigned u = __float_as_uint(f);
    unsigned r = (u + 0x7FFFu + ((u >> 16) & 1u)) >> 16;
    return (unsigned short)r;
}
__device__ __forceinline__ float b2f(unsigned short h) {
    return __uint_as_float(((unsigned)h) << 16);
}
__device__ __forceinline__ void load_lds16(const void* g, void* l) {
    __builtin_amdgcn_global_load_lds((const __attribute__((address_space(1))) void*)g,
                                     (__attribute__((address_space(3))) void*)l, 16, 0, 0);
}

// ===========================================================================
// NEW PATH (templated on SRC; both variants launched, wrong one exits early)
// ===========================================================================

template<int SRC>
__global__ void convert_xw(const float* __restrict__ x0, const float* __restrict__ x1,
                           const float* __restrict__ pb0, const float* __restrict__ pb1,
                           const float* __restrict__ w0, const float* __restrict__ w1,
                           const int* __restrict__ srcp,
                           unsigned short* __restrict__ xb, unsigned short* __restrict__ wb)
{
    if (*srcp != SRC) return;
    constexpr int D = SRC ? DIM1 : DIM0;
    const float* __restrict__ x  = SRC ? x1  : x0;
    const float* __restrict__ pb = SRC ? pb1 : pb0;
    const float* __restrict__ w  = SRC ? w1  : w0;
    const int nx4 = BATCH * D / 4;
    const int nw4 = HIDDEN * D / 4;
    for (int i = blockIdx.x * blockDim.x + threadIdx.x; i < nx4 + nw4;
         i += gridDim.x * blockDim.x) {
        if (i < nx4) {
            float4 v = ((const float4*)x)[i];
            const int k = (i * 4) % D;             // constexpr D -> cheap
            v.x -= pb[k]; v.y -= pb[k + 1]; v.z -= pb[k + 2]; v.w -= pb[k + 3];
            ushort4 o; o.x = f2b(v.x); o.y = f2b(v.y); o.z = f2b(v.z); o.w = f2b(v.w);
            ((ushort4*)xb)[i] = o;
        } else {
            const float4 v = ((const float4*)w)[i - nx4];
            ushort4 o; o.x = f2b(v.x); o.y = f2b(v.y); o.z = f2b(v.z); o.w = f2b(v.w);
            ((ushort4*)wb)[i - nx4] = o;
        }
    }
}

__global__ void transpose_dec_bf16(const float* __restrict__ dec,
                                   unsigned short* __restrict__ decT, int DD)
{
    __shared__ float t[32][33];
    const int hb = blockIdx.x * 32, db = blockIdx.y * 32;
    const int lx = threadIdx.x, ly = threadIdx.y;
#pragma unroll
    for (int s = 0; s < 32; s += 8)
        t[ly + s][lx] = dec[(size_t)(db + ly + s) * HIDDEN + hb + lx];
    __syncthreads();
#pragma unroll
    for (int s = 0; s < 32; s += 8)
        decT[(size_t)(hb + ly + s) * DD + db + lx] = f2b(t[lx][ly + s]);
}

// ---- bf16 MFMA GEMM; stores bf16 scores into first 16KB of each fp32 z row ----
template<int SRC>
__global__ __launch_bounds__(256, 2)
void gemm_bf16(const unsigned short* __restrict__ xb, const unsigned short* __restrict__ wb,
               const int* __restrict__ srcp, float* __restrict__ z)
{
    if (*srcp != SRC) return;
    constexpr int D = SRC ? DIM1 : DIM0;

    __shared__ unsigned short As[128 * 64];
    __shared__ unsigned short Bs[128 * 64];

    const int nwg = gridDim.x;
    int id = blockIdx.x;
    id = (id & 7) * (nwg >> 3) + (id >> 3);      // XCD swizzle (nwg % 8 == 0)
    const int bx = id & 63;
    const int by = id >> 6;
    const int m0 = by * 128, n0 = bx * 128;

    const int tid  = threadIdx.x;
    const int lane = tid & 63;
    const int wid  = tid >> 6;
    const int wr   = wid >> 1;
    const int wc   = wid & 1;
    const int l15  = lane & 15;
    const int g    = lane >> 4;

    f32x4 acc[4][4];
#pragma unroll
    for (int i = 0; i < 4; ++i)
#pragma unroll
        for (int j = 0; j < 4; ++j) acc[i][j] = (f32x4){0.f, 0.f, 0.f, 0.f};

    for (int k0 = 0; k0 < D; k0 += 64) {
#pragma unroll
        for (int q = 0; q < 4; ++q) {
            const int c   = wid * 256 + q * 64 + lane;
            const int row = c >> 3, jb = c & 7;
            const int j   = jb ^ (row & 7);      // pre-swizzled source (rule #21)
            load_lds16(xb + (size_t)(m0 + row) * D + k0 + j * 8,
                       As + (size_t)(wid * 256 + q * 64) * 8);
            load_lds16(wb + (size_t)(n0 + row) * D + k0 + j * 8,
                       Bs + (size_t)(wid * 256 + q * 64) * 8);
        }
        __syncthreads();

#pragma unroll
        for (int kk = 0; kk < 2; ++kk) {
            bf16x8 a[4], b[4];
#pragma unroll
            for (int f = 0; f < 4; ++f) {
                const int rA = wr * 64 + f * 16 + l15;
                const int sA = ((kk * 4 + g) ^ (rA & 7)) * 16;
                a[f] = *(const bf16x8*)((const char*)As + rA * 128 + sA);
                const int rB = wc * 64 + f * 16 + l15;
                const int sB = ((kk * 4 + g) ^ (rB & 7)) * 16;
                b[f] = *(const bf16x8*)((const char*)Bs + rB * 128 + sB);
            }
#pragma unroll
            for (int fi = 0; fi < 4; ++fi)
#pragma unroll
                for (int fj = 0; fj < 4; ++fj)
                    acc[fi][fj] = __builtin_amdgcn_mfma_f32_16x16x32_bf16(
                        a[fi], b[fj], acc[fi][fj], 0, 0, 0);
        }
        __syncthreads();
    }

#pragma unroll
    for (int fi = 0; fi < 4; ++fi) {
        const int row = m0 + wr * 64 + fi * 16 + g * 4;
#pragma unroll
        for (int fj = 0; fj < 4; ++fj) {
            const int col = n0 + wc * 64 + fj * 16 + l15;
#pragma unroll
            for (int r = 0; r < 4; ++r) {
                unsigned short* zs =
                    (unsigned short*)((char*)z + (size_t)(row + r) * (HIDDEN * 4));
                zs[col] = f2b(acc[fi][fj][r]);
            }
        }
    }
}

// ---- per-row: seeded bisect -> candidates -> unrolled exact fp32 rescore
//      -> exact top-32 -> sparse z + vectorized decode ----
template<int SRC>
__global__ __launch_bounds__(256)
void topk_rescore_decode(float* __restrict__ z,
                         const float* __restrict__ x0, const float* __restrict__ x1,
                         const float* __restrict__ pb0, const float* __restrict__ pb1,
                         const float* __restrict__ ew0, const float* __restrict__ ew1,
                         const unsigned short* __restrict__ dTb0,
                         const unsigned short* __restrict__ dTb1,
                         const float* __restrict__ po0, const float* __restrict__ po1,
                         float* __restrict__ rec0, float* __restrict__ rec1,
                         const int* __restrict__ srcp)
{
    if (*srcp != SRC) return;
    constexpr int D = SRC ? DIM1 : DIM0;
    const float* __restrict__ xsrc = SRC ? x1 : x0;
    const float* __restrict__ pb   = SRC ? pb1 : pb0;
    const float* __restrict__ ew   = SRC ? ew1 : ew0;

    __shared__ float         xs[D];
    __shared__ int           cidx[CAND_MAX];
    __shared__ float         cval[CAND_MAX];
    __shared__ unsigned char cflag[CAND_MAX];
    __shared__ int           counts[2][4];
    __shared__ unsigned      pcounts[4];
    __shared__ int           s_cnt;
    __shared__ float         selv[TOPK];
    __shared__ int           seli[TOPK];

    const int tid = threadIdx.x;
    const size_t row = blockIdx.x;
    float* __restrict__ zrow = z + row * HIDDEN;
    const unsigned short* __restrict__ zsrow =
        (const unsigned short*)((const char*)z + row * (HIDDEN * 4));

    // 32 bf16 keys per thread (NT 16B loads; keys then live in registers)
    unsigned key[32];
#pragma unroll
    for (int s = 0; s < 4; ++s) {
        const u16x8 v = __builtin_nontemporal_load(
            (const u16x8*)(zsrow + (size_t)(s * 256 + tid) * 8));
#pragma unroll
        for (int j = 0; j < 8; ++j) key[s * 8 + j] = fkey16(v[j]);
    }

    // zero-fill own z slots now (key data already consumed into registers).
    // Write latency hides under bisect.
    const f32x4 zv4 = (f32x4){0.f, 0.f, 0.f, 0.f};
#pragma unroll
    for (int s = 0; s < 8; ++s)
        __builtin_nontemporal_store(zv4, (f32x4*)&zrow[(size_t)(s * 256 + tid) * 4]);

    // stage exact (x - pb) row: one float4 per thread (D/4 <= 192)
    if (tid < D / 4) {
        const float4 xv = ((const float4*)(xsrc + row * D))[tid];
        const float4 pv = ((const float4*)pb)[tid];
        ((float4*)xs)[tid] = make_float4(xv.x - pv.x, xv.y - pv.y,
                                         xv.z - pv.z, xv.w - pv.w);
    }
    if (tid == 0) s_cnt = 0;

    // ---- seeded probe: count two fixed kappas in one pass ----
    {
        int clo = 0, chi = 0;
#pragma unroll
        for (int j = 0; j < 32; ++j) {
            clo += (key[j] > KLO_G) ? 1 : 0;
            chi += (key[j] > KHI_G) ? 1 : 0;
        }
        unsigned pk = (unsigned)clo | ((unsigned)chi << 16);
#pragma unroll
        for (int off = 32; off; off >>= 1) pk += __shfl_xor(pk, off);
        if ((tid & 63) == 0) pcounts[tid >> 6] = pk;
    }
    __syncthreads();
    const unsigned ptot = pcounts[0] + pcounts[1] + pcounts[2] + pcounts[3];
    const int tot_lo = (int)(ptot & 0xFFFFu), tot_hi = (int)(ptot >> 16);

    unsigned kappa;
    int found = 0;
    if (tot_lo >= WIN_LO && tot_lo <= WIN_HI)      { kappa = KLO_G; found = 1; }
    else if (tot_hi >= WIN_LO && tot_hi <= WIN_HI) { kappa = KHI_G; found = 1; }
    if (!found) {
        unsigned lo = 0u, hi = 65535u;
        if (tot_lo > WIN_HI) lo = KLO_G;
        if (tot_lo < WIN_LO) hi = KLO_G;
        if (tot_hi > WIN_HI) lo = KHI_G;
        if (tot_hi < WIN_LO) hi = (hi < KHI_G) ? hi : KHI_G;
        kappa = lo;
        for (int it = 0; it < 18; ++it) {
            const unsigned mid = (lo + hi) >> 1;
            int c = 0;
#pragma unroll
            for (int j = 0; j < 32; ++j) c += (key[j] > mid) ? 1 : 0;
#pragma unroll
            for (int off = 32; off; off >>= 1) c += __shfl_xor(c, off);
            if ((tid & 63) == 0) counts[it & 1][tid >> 6] = c;
            __syncthreads();                       // single barrier per iter (parity buf)
            const int tot = counts[it & 1][0] + counts[it & 1][1] +
                            counts[it & 1][2] + counts[it & 1][3];
            if (tot >= WIN_LO && tot <= WIN_HI) { kappa = mid; break; }
            if (tot > WIN_HI) lo = mid; else hi = mid;
            kappa = lo;                            // count(lo) > WIN_HI invariant
            if (hi - lo <= 1u) break;              // uniform across block
        }
    }

    // collect candidate indices
#pragma unroll
    for (int j = 0; j < 32; ++j) {
        if (key[j] > kappa) {
            const int slot = atomicAdd(&s_cnt, 1);
            if (slot < CAND_MAX)
                cidx[slot] = ((j >> 3) * 256 + tid) * 8 + (j & 7);
        }
    }
    __syncthreads();
    const int C = min(s_cnt, CAND_MAX);

    // exact fp32 rescore: 8-lane groups, fully-unrolled (constexpr D) streaming
    {
        const int grp = tid >> 3, j8 = tid & 7;
        for (int c = grp; c < C; c += 32) {
            const float* __restrict__ wrow = ew + (size_t)cidx[c] * D;
            float4 a4 = make_float4(0.f, 0.f, 0.f, 0.f);
#pragma unroll
            for (int s = 0; s < D; s += 32) {
                const float4 w4 = *(const float4*)&wrow[s + j8 * 4];
                const float4 x4 = *(const float4*)&xs[s + j8 * 4];
                a4.x = fmaf(x4.x, w4.x, a4.x);
                a4.y = fmaf(x4.y, w4.y, a4.y);
                a4.z = fmaf(x4.z, w4.z, a4.z);
                a4.w = fmaf(x4.w, w4.w, a4.w);
            }
            float a = (a4.x + a4.y) + (a4.z + a4.w);
            a += __shfl_xor(a, 1);
            a += __shfl_xor(a, 2);
            a += __shfl_xor(a, 4);
            if (j8 == 0) cval[c] = a;
        }
    }
    __syncthreads();

    // exact top-32 among C candidates (val desc, idx asc)
    if (tid < C) {
        const float v = cval[tid];
        const int  ix = cidx[tid];
        int rank = 0;
        for (int j = 0; j < C; ++j) {
            const float vj = cval[j];
            rank += (vj > v || (vj == v && cidx[j] < ix)) ? 1 : 0;
        }
        cflag[tid] = (rank < TOPK) ? 1 : 0;
    }
    __syncthreads();
    if (tid < C && cflag[tid]) {
        const int ix = cidx[tid];
        int sr = 0;
        for (int j = 0; j < C; ++j) sr += (cflag[j] && cidx[j] < ix) ? 1 : 0;
        selv[sr] = cval[tid];
        seli[sr] = ix;
    }
    __syncthreads();

    // scatter 32 exact values (zero-fill completed long ago; barrier above orders)
    if (tid < TOPK) zrow[seli[tid]] = selv[tid];

    // vectorized sparse decode: thread -> 4 consecutive outputs, ushort4 gathers
#pragma unroll
    for (int pass = 0; pass < 2; ++pass) {
        const int slot = pass * 256 + tid;
        if (slot < (DIM0 + DIM1) / 4) {
            const bool is0 = slot < DIM0 / 4;
            const int d0 = is0 ? slot * 4 : (slot - DIM0 / 4) * 4;
            const int DD = is0 ? DIM0 : DIM1;
            const unsigned short* __restrict__ dT = is0 ? dTb0 : dTb1;
            const float* __restrict__ po = is0 ? po0 : po1;
            f32x4 a;
            {
                const float4 p4 = *(const float4*)&po[d0];
                a = (f32x4){p4.x, p4.y, p4.z, p4.w};
            }
#pragma unroll
            for (int j = 0; j < TOPK; ++j) {
                const float sv = selv[j];
                const ushort4 w4 = *(const ushort4*)&dT[(size_t)seli[j] * DD + d0];
                a.x = fmaf(sv, b2f(w4.x), a.x);
                a.y = fmaf(sv, b2f(w4.y), a.y);
                a.z = fmaf(sv, b2f(w4.z), a.z);
                a.w = fmaf(sv, b2f(w4.w), a.w);
            }
            float* __restrict__ out = is0 ? (rec0 + row * DIM0 + d0)
                                          : (rec1 + row * DIM1 + d0);
            __builtin_nontemporal_store(a, (f32x4*)out);
        }
    }
}

// ===========================================================================
// FALLBACK PATH (round-1, known-pass) — used only if ws is too small
// ===========================================================================

__global__ __launch_bounds__(256, 2)
void encode_gemm(const float* __restrict__ x0, const float* __restrict__ x1,
                 const float* __restrict__ pb0, const float* __restrict__ pb1,
                 const float* __restrict__ w0, const float* __restrict__ w1,
                 const int* __restrict__ srcp, float* __restrict__ z)
{
    const int src = *srcp;
    const float* __restrict__ x  = (src == 0) ? x0 : x1;
    const float* __restrict__ pb = (src == 0) ? pb0 : pb1;
    const float* __restrict__ w  = (src == 0) ? w0 : w1;
    const int D = (src == 0) ? DIM0 : DIM1;

    __shared__ float As[16][132];
    __shared__ float Bs[16][132];

    const int tid = threadIdx.x;
    const int m0 = blockIdx.y * 128;
    const int n0 = blockIdx.x * 128;

    const int cA0 = tid,          cA1 = tid + 256;
    const int r0  = cA0 >> 2,     kq0 = (cA0 & 3) * 4;
    const int r1  = cA1 >> 2,     kq1 = (cA1 & 3) * 4;

    const int mf = (tid & 15) * 4;
    const int nf = (tid >> 4) * 4;

    float acc[8][8];
#pragma unroll
    for (int i = 0; i < 8; ++i)
#pragma unroll
        for (int j = 0; j < 8; ++j) acc[i][j] = 0.0f;

    for (int k0 = 0; k0 < D; k0 += 16) {
        const float4 av0 = *(const float4*)(x + (size_t)(m0 + r0) * D + k0 + kq0);
        const float4 av1 = *(const float4*)(x + (size_t)(m0 + r1) * D + k0 + kq1);
        const float4 pv0 = *(const float4*)(pb + k0 + kq0);
        const float4 pv1 = *(const float4*)(pb + k0 + kq1);
        const float4 bv0 = *(const float4*)(w + (size_t)(n0 + r0) * D + k0 + kq0);
        const float4 bv1 = *(const float4*)(w + (size_t)(n0 + r1) * D + k0 + kq1);
        As[kq0 + 0][r0] = av0.x - pv0.x;
        As[kq0 + 1][r0] = av0.y - pv0.y;
        As[kq0 + 2][r0] = av0.z - pv0.z;
        As[kq0 + 3][r0] = av0.w - pv0.w;
        As[kq1 + 0][r1] = av1.x - pv1.x;
        As[kq1 + 1][r1] = av1.y - pv1.y;
        As[kq1 + 2][r1] = av1.z - pv1.z;
        As[kq1 + 3][r1] = av1.w - pv1.w;
        Bs[kq0 + 0][r0] = bv0.x;
        Bs[kq0 + 1][r0] = bv0.y;
        Bs[kq0 + 2][r0] = bv0.z;
        Bs[kq0 + 3][r0] = bv0.w;
        Bs[kq1 + 0][r1] = bv1.x;
        Bs[kq1 + 1][r1] = bv1.y;
        Bs[kq1 + 2][r1] = bv1.z;
        Bs[kq1 + 3][r1] = bv1.w;
        __syncthreads();
#pragma unroll
        for (int kk = 0; kk < 16; ++kk) {
            const float4 A0 = *(const float4*)&As[kk][mf];
            const float4 A1 = *(const float4*)&As[kk][mf + 64];
            const float4 B0 = *(const float4*)&Bs[kk][nf];
            const float4 B1 = *(const float4*)&Bs[kk][nf + 64];
            const float a[8] = {A0.x, A0.y, A0.z, A0.w, A1.x, A1.y, A1.z, A1.w};
            const float b[8] = {B0.x, B0.y, B0.z, B0.w, B1.x, B1.y, B1.z, B1.w};
#pragma unroll
            for (int i = 0; i < 8; ++i)
#pragma unroll
                for (int j = 0; j < 8; ++j)
                    acc[i][j] = fmaf(a[i], b[j], acc[i][j]);
        }
        __syncthreads();
    }

#pragma unroll
    for (int i = 0; i < 8; ++i) {
        const int row = m0 + mf + (i & 3) + (i >> 2) * 64;
        const float4 v0 = make_float4(acc[i][0], acc[i][1], acc[i][2], acc[i][3]);
        const float4 v1 = make_float4(acc[i][4], acc[i][5], acc[i][6], acc[i][7]);
        *(float4*)(z + (size_t)row * HIDDEN + n0 + nf)      = v0;
        *(float4*)(z + (size_t)row * HIDDEN + n0 + nf + 64) = v1;
    }
}

__global__ __launch_bounds__(256, 2)
void topk_decode_fb(float* __restrict__ z,
                    const float* __restrict__ dA, const float* __restrict__ dB,
                    const float* __restrict__ po0, const float* __restrict__ po1,
                    float* __restrict__ rec0, float* __restrict__ rec1)
{
    __shared__ float    rowv[HIDDEN];
    __shared__ unsigned hist[4][257];
    __shared__ unsigned scanbuf[256];
    __shared__ float    selv[TOPK];
    __shared__ int      seli[TOPK];
    __shared__ unsigned sh_byte, sh_gt;

    const int tid = threadIdx.x;
    const size_t rowid = blockIdx.x;
    float* __restrict__ zrow = z + rowid * HIDDEN;

#pragma unroll
    for (int s = 0; s < 8; ++s) {
        const int i4 = s * 256 + tid;
        *(float4*)&rowv[i4 * 4] = *(const float4*)&zrow[i4 * 4];
    }
    __syncthreads();

    unsigned prefix = 0, prefmask = 0, need = TOPK;
#pragma unroll
    for (int p = 3; p >= 0; --p) {
        for (int i = tid; i < 4 * 257; i += 256) (&hist[0][0])[i] = 0;
        __syncthreads();
        const int sh = p * 8;
        for (int s = 0; s < 32; ++s) {
            const int i = s * 256 + tid;
            const unsigned k = fkey(rowv[i]);
            if ((k & prefmask) == prefix)
                atomicAdd(&hist[tid & 3][(k >> sh) & 255], 1);
        }
        __syncthreads();
        const unsigned tot = hist[0][tid] + hist[1][tid] + hist[2][tid] + hist[3][tid];
        hist[0][tid] = tot;
        __syncthreads();
        if (tid == 0) {
            unsigned cum = 0;
            int b = 255;
            for (;; --b) {
                const unsigned c = hist[0][b];
                if (cum + c >= need || b == 0) { sh_byte = (unsigned)b; sh_gt = cum; break; }
                cum += c;
            }
        }
        __syncthreads();
        prefix  |= sh_byte << sh;
        prefmask |= 0xFFu << sh;
        need -= sh_gt;
        __syncthreads();
    }
    const unsigned cut = prefix;
    const unsigned needEq = need;

    unsigned gtmask = 0, eqmask = 0;
#pragma unroll
    for (int j = 0; j < 32; ++j) {
        const int jr = (j + tid) & 31;
        const int i = tid * 32 + jr;
        const unsigned k = fkey(rowv[i]);
        if (k > cut)       gtmask |= 1u << jr;
        else if (k == cut) eqmask |= 1u << jr;
    }

    scanbuf[tid] = __popc(eqmask);
    __syncthreads();
    for (int off = 1; off < 256; off <<= 1) {
        const unsigned v = scanbuf[tid];
        const unsigned add = (tid >= off) ? scanbuf[tid - off] : 0u;
        __syncthreads();
        scanbuf[tid] = v + add;
        __syncthreads();
    }
    const unsigned eqexc = scanbuf[tid] - __popc(eqmask);
    __syncthreads();

    unsigned selmask = gtmask;
    {
        unsigned m = eqmask, r = eqexc;
        while (m) {
            const int j = __ffs(m) - 1;
            if (r < needEq) selmask |= 1u << j;
            ++r;
            m &= m - 1;
        }
    }

    scanbuf[tid] = __popc(selmask);
    __syncthreads();
    for (int off = 1; off < 256; off <<= 1) {
        const unsigned v = scanbuf[tid];
        const unsigned add = (tid >= off) ? scanbuf[tid - off] : 0u;
        __syncthreads();
        scanbuf[tid] = v + add;
        __syncthreads();
    }
    const unsigned selexc = scanbuf[tid] - __popc(selmask);

#pragma unroll
    for (int j = 0; j < 32; ++j) {
        const int jr = (j + tid) & 31;
        const int i = tid * 32 + jr;
        if ((selmask >> jr) & 1u) {
            const int slot = (int)(selexc + __popc(selmask & ((1u << jr) - 1u)));
            selv[slot] = rowv[i];
            seli[slot] = i;
        } else {
            rowv[i] = 0.0f;
        }
    }
    __syncthreads();

#pragma unroll
    for (int s = 0; s < 8; ++s) {
        const int i4 = s * 256 + tid;
        *(float4*)&zrow[i4 * 4] = *(float4*)&rowv[i4 * 4];
    }

    for (int d = tid; d < DIM0; d += 256) {
        float a = po0[d];
#pragma unroll
        for (int j = 0; j < TOPK; ++j)
            a = fmaf(selv[j], dA[(size_t)d * HIDDEN + seli[j]], a);
        rec0[rowid * DIM0 + d] = a;
    }
    for (int d = tid; d < DIM1; d += 256) {
        float a = po1[d];
#pragma unroll
        for (int j = 0; j < TOPK; ++j)
            a = fmaf(selv[j], dB[(size_t)d * HIDDEN + seli[j]], a);
        rec1[rowid * DIM1 + d] = a;
    }
}

// ===========================================================================
extern "C" void kernel_launch(void* const* d_in, const int* in_sizes, int n_in,
                              void* d_out, int out_size, void* d_ws, size_t ws_size,
                              hipStream_t stream)
{
    const float* x0  = (const float*)d_in[0];
    const float* x1  = (const float*)d_in[1];
    const float* pb0 = (const float*)d_in[2];
    const float* pb1 = (const float*)d_in[3];
    const float* ew0 = (const float*)d_in[4];
    const float* ew1 = (const float*)d_in[5];
    const float* dw0 = (const float*)d_in[6];
    const float* dw1 = (const float*)d_in[7];
    const float* po0 = (const float*)d_in[8];
    const float* po1 = (const float*)d_in[9];
    const int*  srcp = (const int*)d_in[10];

    float* z    = (float*)d_out;
    float* rec0 = z + (size_t)BATCH * HIDDEN;
    float* rec1 = rec0 + (size_t)BATCH * DIM0;

    // ws layout (bf16): xb[B][768] | wb[H][768] | dTb0[H][512] | dTb1[H][768]
    unsigned short* xb   = (unsigned short*)d_ws;
    unsigned short* wb   = xb   + (size_t)BATCH * DIM1;
    unsigned short* dTb0 = wb   + (size_t)HIDDEN * DIM1;
    unsigned short* dTb1 = dTb0 + (size_t)HIDDEN * DIM0;
    const size_t need = ((size_t)BATCH * DIM1 + (size_t)HIDDEN * DIM1 +
                         (size_t)HIDDEN * DIM0 + (size_t)HIDDEN * DIM1) * sizeof(unsigned short);

    if (ws_size >= need) {
        convert_xw<0><<<4096, 256, 0, stream>>>(x0, x1, pb0, pb1, ew0, ew1, srcp, xb, wb);
        convert_xw<1><<<4096, 256, 0, stream>>>(x0, x1, pb0, pb1, ew0, ew1, srcp, xb, wb);
        dim3 tb(32, 8);
        transpose_dec_bf16<<<dim3(HIDDEN / 32, DIM0 / 32), tb, 0, stream>>>(dw0, dTb0, DIM0);
        transpose_dec_bf16<<<dim3(HIDDEN / 32, DIM1 / 32), tb, 0, stream>>>(dw1, dTb1, DIM1);
        gemm_bf16<0><<<(BATCH / 128) * (HIDDEN / 128), 256, 0, stream>>>(xb, wb, srcp, z);
        gemm_bf16<1><<<(BATCH / 128) * (HIDDEN / 128), 256, 0, stream>>>(xb, wb, srcp, z);
        topk_rescore_decode<0><<<BATCH, 256, 0, stream>>>(
            z, x0, x1, pb0, pb1, ew0, ew1, dTb0, dTb1, po0, po1, rec0, rec1, srcp);
        topk_rescore_decode<1><<<BATCH, 256, 0, stream>>>(
            z, x0, x1, pb0, pb1, ew0, ew1, dTb0, dTb1, po0, po1, rec0, rec1, srcp);
    } else {
        encode_gemm<<<dim3(HIDDEN / 128, BATCH / 128), 256, 0, stream>>>(
            x0, x1, pb0, pb1, ew0, ew1, srcp, z);
        topk_decode_fb<<<BATCH, 256, 0, stream>>>(z, dw0, dw1, po0, po1, rec0, rec1);
    }
}

// Round 6
// 749.971 us; speedup vs baseline: 1.0366x; 1.0366x over previous
//
#include <hip/hip_runtime.h>

// UniversalSAE: z = TopK32((x - pre_bias) @ enc_w.T), rec_i = z @ dec_w_i.T + post_bias_i
// R6: single-dispatch runtime-branch kernels (constexpr D inside), packed u16 keys
// (VGPR<=64 -> 8 waves/SIMD), plain cacheable score loads (NT loads regressed R5),
// GEMM zeroes back half of z rows, tightened candidate window [36,64].

#define BATCH  16384
#define HIDDEN 8192
#define DIM0   512
#define DIM1   768
#define TOPK   32
#define CAND_MAX 256
#define WIN_LO 36
#define WIN_HI 64

// probe seeds: fkey16(bf16(0.4)) and fkey16(bf16(2.5)); correctness independent of values
#define KLO_G 0xBECDu
#define KHI_G 0xC020u

typedef __attribute__((ext_vector_type(8))) short bf16x8;
typedef __attribute__((ext_vector_type(8))) unsigned short u16x8;
typedef __attribute__((ext_vector_type(4))) float f32x4;

__device__ __forceinline__ unsigned fkey(float f) {
    unsigned u = __float_as_uint(f);
    return (u & 0x80000000u) ? ~u : (u | 0x80000000u);
}
__device__ __forceinline__ unsigned fkey16(unsigned short h) {
    return (h & 0x8000u) ? (unsigned)((~h) & 0xFFFFu) : (unsigned)(h | 0x8000u);
}
__device__ __forceinline__ unsigned short f2b(float f) {  // fp32 -> bf16 RNE
    unsigned u = __float_as_uint(f);
    unsigned r = (u + 0x7FFFu + ((u >> 16) & 1u)) >> 16;
    return (unsigned short)r;
}
__device__ __forceinline__ float b2f(unsigned short h) {
    return __uint_as_float(((unsigned)h) << 16);
}
__device__ __forceinline__ void load_lds16(const void* g, void* l) {
    __builtin_amdgcn_global_load_lds((const __attribute__((address_space(1))) void*)g,
                                     (__attribute__((address_space(3))) void*)l, 16, 0, 0);
}

// ===========================================================================
// convert: x-pb and enc_w to bf16 (runtime branch -> constexpr D impls)
// ===========================================================================
template<int SRC>
__device__ __forceinline__ void convert_impl(
    const float* __restrict__ x, const float* __restrict__ pb,
    const float* __restrict__ w,
    unsigned short* __restrict__ xb, unsigned short* __restrict__ wb)
{
    constexpr int D = SRC ? DIM1 : DIM0;
    const int nx4 = BATCH * D / 4;
    const int nw4 = HIDDEN * D / 4;
    for (int i = blockIdx.x * blockDim.x + threadIdx.x; i < nx4 + nw4;
         i += gridDim.x * blockDim.x) {
        if (i < nx4) {
            float4 v = ((const float4*)x)[i];
            const int k = (i * 4) % D;
            v.x -= pb[k]; v.y -= pb[k + 1]; v.z -= pb[k + 2]; v.w -= pb[k + 3];
            ushort4 o; o.x = f2b(v.x); o.y = f2b(v.y); o.z = f2b(v.z); o.w = f2b(v.w);
            ((ushort4*)xb)[i] = o;
        } else {
            const float4 v = ((const float4*)w)[i - nx4];
            ushort4 o; o.x = f2b(v.x); o.y = f2b(v.y); o.z = f2b(v.z); o.w = f2b(v.w);
            ((ushort4*)wb)[i - nx4] = o;
        }
    }
}

__global__ void convert_xw(const float* __restrict__ x0, const float* __restrict__ x1,
                           const float* __restrict__ pb0, const float* __restrict__ pb1,
                           const float* __restrict__ w0, const float* __restrict__ w1,
                           const int* __restrict__ srcp,
                           unsigned short* __restrict__ xb, unsigned short* __restrict__ wb)
{
    if (*srcp == 0) convert_impl<0>(x0, pb0, w0, xb, wb);
    else            convert_impl<1>(x1, pb1, w1, xb, wb);
}

__global__ void transpose_dec_bf16(const float* __restrict__ dec,
                                   unsigned short* __restrict__ decT, int DD)
{
    __shared__ float t[32][33];
    const int hb = blockIdx.x * 32, db = blockIdx.y * 32;
    const int lx = threadIdx.x, ly = threadIdx.y;
#pragma unroll
    for (int s = 0; s < 32; s += 8)
        t[ly + s][lx] = dec[(size_t)(db + ly + s) * HIDDEN + hb + lx];
    __syncthreads();
#pragma unroll
    for (int s = 0; s < 32; s += 8)
        decT[(size_t)(hb + ly + s) * DD + db + lx] = f2b(t[lx][ly + s]);
}

// ===========================================================================
// GEMM: bf16 scores into first 16KB of each fp32 z row; blocks bx>=32 also
// NT-zero the back half (fp32 cols 4096..8191) of their 128 rows.
// ===========================================================================
template<int SRC>
__device__ __forceinline__ void gemm_impl(
    const unsigned short* __restrict__ xb, const unsigned short* __restrict__ wb,
    float* __restrict__ z, unsigned short* As, unsigned short* Bs)
{
    constexpr int D = SRC ? DIM1 : DIM0;

    const int nwg = gridDim.x;
    int id = blockIdx.x;
    id = (id & 7) * (nwg >> 3) + (id >> 3);      // XCD swizzle (nwg % 8 == 0)
    const int bx = id & 63;
    const int by = id >> 6;
    const int m0 = by * 128, n0 = bx * 128;

    const int tid  = threadIdx.x;
    const int lane = tid & 63;
    const int wid  = tid >> 6;
    const int wr   = wid >> 1;
    const int wc   = wid & 1;
    const int l15  = lane & 15;
    const int g    = lane >> 4;

    f32x4 acc[4][4];
#pragma unroll
    for (int i = 0; i < 4; ++i)
#pragma unroll
        for (int j = 0; j < 4; ++j) acc[i][j] = (f32x4){0.f, 0.f, 0.f, 0.f};

    for (int k0 = 0; k0 < D; k0 += 64) {
#pragma unroll
        for (int q = 0; q < 4; ++q) {
            const int c   = wid * 256 + q * 64 + lane;
            const int row = c >> 3, jb = c & 7;
            const int j   = jb ^ (row & 7);      // pre-swizzled source (rule #21)
            load_lds16(xb + (size_t)(m0 + row) * D + k0 + j * 8,
                       As + (size_t)(wid * 256 + q * 64) * 8);
            load_lds16(wb + (size_t)(n0 + row) * D + k0 + j * 8,
                       Bs + (size_t)(wid * 256 + q * 64) * 8);
        }
        __syncthreads();

#pragma unroll
        for (int kk = 0; kk < 2; ++kk) {
            bf16x8 a[4], b[4];
#pragma unroll
            for (int f = 0; f < 4; ++f) {
                const int rA = wr * 64 + f * 16 + l15;
                const int sA = ((kk * 4 + g) ^ (rA & 7)) * 16;
                a[f] = *(const bf16x8*)((const char*)As + rA * 128 + sA);
                const int rB = wc * 64 + f * 16 + l15;
                const int sB = ((kk * 4 + g) ^ (rB & 7)) * 16;
                b[f] = *(const bf16x8*)((const char*)Bs + rB * 128 + sB);
            }
#pragma unroll
            for (int fi = 0; fi < 4; ++fi)
#pragma unroll
                for (int fj = 0; fj < 4; ++fj)
                    acc[fi][fj] = __builtin_amdgcn_mfma_f32_16x16x32_bf16(
                        a[fi], b[fj], acc[fi][fj], 0, 0, 0);
        }
        __syncthreads();
    }

    // epilogue: bf16 scores at byte offset row*(HIDDEN*4), col*2
#pragma unroll
    for (int fi = 0; fi < 4; ++fi) {
        const int row = m0 + wr * 64 + fi * 16 + g * 4;
#pragma unroll
        for (int fj = 0; fj < 4; ++fj) {
            const int col = n0 + wc * 64 + fj * 16 + l15;
#pragma unroll
            for (int r = 0; r < 4; ++r) {
                unsigned short* zs =
                    (unsigned short*)((char*)z + (size_t)(row + r) * (HIDDEN * 4));
                zs[col] = f2b(acc[fi][fj][r]);
            }
        }
    }

    // back-half zero: fp32 cols [4096 + (bx-32)*128, +128) for rows [m0, m0+128)
    if (bx >= 32) {
        const f32x4 zv = (f32x4){0.f, 0.f, 0.f, 0.f};
        const int c4 = (4096 >> 2) + (bx - 32) * 32 + (tid & 31);  // f32x4 index in row
#pragma unroll
        for (int pass = 0; pass < 16; ++pass) {
            const int r = m0 + pass * 8 + (tid >> 5);
            __builtin_nontemporal_store(zv, (f32x4*)(z + (size_t)r * HIDDEN) + c4);
        }
    }
}

__global__ __launch_bounds__(256, 2)
void gemm_bf16(const unsigned short* __restrict__ xb, const unsigned short* __restrict__ wb,
               const int* __restrict__ srcp, float* __restrict__ z)
{
    __shared__ unsigned short As[128 * 64];
    __shared__ unsigned short Bs[128 * 64];
    if (*srcp == 0) gemm_impl<0>(xb, wb, z, As, Bs);
    else            gemm_impl<1>(xb, wb, z, As, Bs);
}

// ===========================================================================
// topk: seeded bisect (packed u16 keys) -> candidates -> exact fp32 rescore
//       -> exact top-32 -> front-half zero + scatter + vectorized decode
// ===========================================================================
template<int SRC>
__device__ __forceinline__ void topk_impl(
    float* __restrict__ z,
    const float* __restrict__ xsrc, const float* __restrict__ pb,
    const float* __restrict__ ew,
    const unsigned short* __restrict__ dTb0, const unsigned short* __restrict__ dTb1,
    const float* __restrict__ po0, const float* __restrict__ po1,
    float* __restrict__ rec0, float* __restrict__ rec1,
    float* xs, int* cidx, float* cval, unsigned char* cflag,
    int* counts, unsigned* pcounts, int* s_cnt, float* selv, int* seli)
{
    constexpr int D = SRC ? DIM1 : DIM0;

    const int tid = threadIdx.x;
    const size_t row = blockIdx.x;
    float* __restrict__ zrow = z + row * HIDDEN;
    const unsigned short* __restrict__ zsrow =
        (const unsigned short*)((const char*)z + row * (HIDDEN * 4));

    // 32 bf16 keys per thread, PACKED two-per-u32 (16 VGPRs)
    unsigned pkey[16];
#pragma unroll
    for (int s = 0; s < 4; ++s) {
        const u16x8 v = *(const u16x8*)(zsrow + (size_t)(s * 256 + tid) * 8);
#pragma unroll
        for (int p = 0; p < 4; ++p)
            pkey[s * 4 + p] = fkey16(v[2 * p]) | (fkey16(v[2 * p + 1]) << 16);
    }

    // zero-fill own slots of the FRONT half (cols 0..4095 = the score bytes).
    // Back half already zeroed by the GEMM. Write latency hides under bisect.
    const f32x4 zv4 = (f32x4){0.f, 0.f, 0.f, 0.f};
#pragma unroll
    for (int s = 0; s < 4; ++s)
        __builtin_nontemporal_store(zv4, (f32x4*)&zrow[(size_t)(s * 256 + tid) * 4]);

    // stage exact (x - pb) row: one float4 per thread (D/4 <= 192)
    if (tid < D / 4) {
        const float4 xv = ((const float4*)(xsrc + row * D))[tid];
        const float4 pv = ((const float4*)pb)[tid];
        ((float4*)xs)[tid] = make_float4(xv.x - pv.x, xv.y - pv.y,
                                         xv.z - pv.z, xv.w - pv.w);
    }
    if (tid == 0) *s_cnt = 0;

    // ---- seeded probe: count two fixed kappas in one pass ----
    {
        int clo = 0, chi = 0;
#pragma unroll
        for (int p = 0; p < 16; ++p) {
            const unsigned klo16 = pkey[p] & 0xFFFFu, khi16 = pkey[p] >> 16;
            clo += (klo16 > KLO_G) ? 1 : 0;  chi += (klo16 > KHI_G) ? 1 : 0;
            clo += (khi16 > KLO_G) ? 1 : 0;  chi += (khi16 > KHI_G) ? 1 : 0;
        }
        unsigned pk = (unsigned)clo | ((unsigned)chi << 16);
#pragma unroll
        for (int off = 32; off; off >>= 1) pk += __shfl_xor(pk, off);
        if ((tid & 63) == 0) pcounts[tid >> 6] = pk;
    }
    __syncthreads();
    const unsigned ptot = pcounts[0] + pcounts[1] + pcounts[2] + pcounts[3];
    const int tot_lo = (int)(ptot & 0xFFFFu), tot_hi = (int)(ptot >> 16);

    unsigned kappa;
    int found = 0;
    if (tot_lo >= WIN_LO && tot_lo <= WIN_HI)      { kappa = KLO_G; found = 1; }
    else if (tot_hi >= WIN_LO && tot_hi <= WIN_HI) { kappa = KHI_G; found = 1; }
    if (!found) {
        unsigned lo = 0u, hi = 65535u;
        if (tot_lo > WIN_HI) lo = KLO_G;
        if (tot_lo < WIN_LO) hi = KLO_G;
        if (tot_hi > WIN_HI) lo = KHI_G;
        if (tot_hi < WIN_LO) hi = (hi < KHI_G) ? hi : KHI_G;
        kappa = lo;
        for (int it = 0; it < 18; ++it) {
            const unsigned mid = (lo + hi) >> 1;
            int c = 0;
#pragma unroll
            for (int p = 0; p < 16; ++p) {
                c += ((pkey[p] & 0xFFFFu) > mid) ? 1 : 0;
                c += ((pkey[p] >> 16)     > mid) ? 1 : 0;
            }
#pragma unroll
            for (int off = 32; off; off >>= 1) c += __shfl_xor(c, off);
            if ((tid & 63) == 0) counts[(it & 1) * 4 + (tid >> 6)] = c;
            __syncthreads();                       // single barrier per iter (parity buf)
            const int* cb = counts + (it & 1) * 4;
            const int tot = cb[0] + cb[1] + cb[2] + cb[3];
            if (tot >= WIN_LO && tot <= WIN_HI) { kappa = mid; break; }
            if (tot > WIN_HI) lo = mid; else hi = mid;
            kappa = lo;                            // count(lo) > WIN_HI invariant
            if (hi - lo <= 1u) break;              // uniform across block
        }
    }

    // collect candidate indices (key j=2p+h, element ((j>>3)*256+tid)*8 + (j&7))
#pragma unroll
    for (int p = 0; p < 16; ++p) {
#pragma unroll
        for (int h = 0; h < 2; ++h) {
            const unsigned k16 = h ? (pkey[p] >> 16) : (pkey[p] & 0xFFFFu);
            if (k16 > kappa) {
                const int j = 2 * p + h;
                const int slot = atomicAdd(s_cnt, 1);
                if (slot < CAND_MAX)
                    cidx[slot] = ((j >> 3) * 256 + tid) * 8 + (j & 7);
            }
        }
    }
    __syncthreads();
    const int C = min(*s_cnt, CAND_MAX);

    // exact fp32 rescore: 8-lane groups, fully-unrolled (constexpr D) streaming
    {
        const int grp = tid >> 3, j8 = tid & 7;
        for (int c = grp; c < C; c += 32) {
            const float* __restrict__ wrow = ew + (size_t)cidx[c] * D;
            float4 a4 = make_float4(0.f, 0.f, 0.f, 0.f);
#pragma unroll
            for (int s = 0; s < D; s += 32) {
                const float4 w4 = *(const float4*)&wrow[s + j8 * 4];
                const float4 x4 = *(const float4*)&xs[s + j8 * 4];
                a4.x = fmaf(x4.x, w4.x, a4.x);
                a4.y = fmaf(x4.y, w4.y, a4.y);
                a4.z = fmaf(x4.z, w4.z, a4.z);
                a4.w = fmaf(x4.w, w4.w, a4.w);
            }
            float a = (a4.x + a4.y) + (a4.z + a4.w);
            a += __shfl_xor(a, 1);
            a += __shfl_xor(a, 2);
            a += __shfl_xor(a, 4);
            if (j8 == 0) cval[c] = a;
        }
    }
    __syncthreads();

    // exact top-32 among C candidates (val desc, idx asc)
    if (tid < C) {
        const float v = cval[tid];
        const int  ix = cidx[tid];
        int rank = 0;
        for (int j = 0; j < C; ++j) {
            const float vj = cval[j];
            rank += (vj > v || (vj == v && cidx[j] < ix)) ? 1 : 0;
        }
        cflag[tid] = (rank < TOPK) ? 1 : 0;
    }
    __syncthreads();
    if (tid < C && cflag[tid]) {
        const int ix = cidx[tid];
        int sr = 0;
        for (int j = 0; j < C; ++j) sr += (cflag[j] && cidx[j] < ix) ? 1 : 0;
        selv[sr] = cval[tid];
        seli[sr] = ix;
    }
    __syncthreads();

    // scatter 32 exact values (front zero done above, back half by GEMM)
    if (tid < TOPK) zrow[seli[tid]] = selv[tid];

    // vectorized sparse decode: thread -> 4 consecutive outputs, ushort4 gathers
#pragma unroll
    for (int pass = 0; pass < 2; ++pass) {
        const int slot = pass * 256 + tid;
        if (slot < (DIM0 + DIM1) / 4) {
            const bool is0 = slot < DIM0 / 4;
            const int d0 = is0 ? slot * 4 : (slot - DIM0 / 4) * 4;
            const int DD = is0 ? DIM0 : DIM1;
            const unsigned short* __restrict__ dT = is0 ? dTb0 : dTb1;
            const float* __restrict__ po = is0 ? po0 : po1;
            f32x4 a;
            {
                const float4 p4 = *(const float4*)&po[d0];
                a = (f32x4){p4.x, p4.y, p4.z, p4.w};
            }
#pragma unroll
            for (int j = 0; j < TOPK; ++j) {
                const float sv = selv[j];
                const ushort4 w4 = *(const ushort4*)&dT[(size_t)seli[j] * DD + d0];
                a.x = fmaf(sv, b2f(w4.x), a.x);
                a.y = fmaf(sv, b2f(w4.y), a.y);
                a.z = fmaf(sv, b2f(w4.z), a.z);
                a.w = fmaf(sv, b2f(w4.w), a.w);
            }
            float* __restrict__ out = is0 ? (rec0 + row * DIM0 + d0)
                                          : (rec1 + row * DIM1 + d0);
            __builtin_nontemporal_store(a, (f32x4*)out);
        }
    }
}

__global__ __launch_bounds__(256)
void topk_rescore_decode(float* __restrict__ z,
                         const float* __restrict__ x0, const float* __restrict__ x1,
                         const float* __restrict__ pb0, const float* __restrict__ pb1,
                         const float* __restrict__ ew0, const float* __restrict__ ew1,
                         const unsigned short* __restrict__ dTb0,
                         const unsigned short* __restrict__ dTb1,
                         const float* __restrict__ po0, const float* __restrict__ po1,
                         float* __restrict__ rec0, float* __restrict__ rec1,
                         const int* __restrict__ srcp)
{
    __shared__ float         xs[DIM1];
    __shared__ int           cidx[CAND_MAX];
    __shared__ float         cval[CAND_MAX];
    __shared__ unsigned char cflag[CAND_MAX];
    __shared__ int           counts[2 * 4];
    __shared__ unsigned      pcounts[4];
    __shared__ int           s_cnt;
    __shared__ float         selv[TOPK];
    __shared__ int           seli[TOPK];

    if (*srcp == 0)
        topk_impl<0>(z, x0, pb0, ew0, dTb0, dTb1, po0, po1, rec0, rec1,
                     xs, cidx, cval, cflag, counts, pcounts, &s_cnt, selv, seli);
    else
        topk_impl<1>(z, x1, pb1, ew1, dTb0, dTb1, po0, po1, rec0, rec1,
                     xs, cidx, cval, cflag, counts, pcounts, &s_cnt, selv, seli);
}

// ===========================================================================
// FALLBACK PATH (round-1, known-pass) — used only if ws is too small
// ===========================================================================

__global__ __launch_bounds__(256, 2)
void encode_gemm(const float* __restrict__ x0, const float* __restrict__ x1,
                 const float* __restrict__ pb0, const float* __restrict__ pb1,
                 const float* __restrict__ w0, const float* __restrict__ w1,
                 const int* __restrict__ srcp, float* __restrict__ z)
{
    const int src = *srcp;
    const float* __restrict__ x  = (src == 0) ? x0 : x1;
    const float* __restrict__ pb = (src == 0) ? pb0 : pb1;
    const float* __restrict__ w  = (src == 0) ? w0 : w1;
    const int D = (src == 0) ? DIM0 : DIM1;

    __shared__ float As[16][132];
    __shared__ float Bs[16][132];

    const int tid = threadIdx.x;
    const int m0 = blockIdx.y * 128;
    const int n0 = blockIdx.x * 128;

    const int cA0 = tid,          cA1 = tid + 256;
    const int r0  = cA0 >> 2,     kq0 = (cA0 & 3) * 4;
    const int r1  = cA1 >> 2,     kq1 = (cA1 & 3) * 4;

    const int mf = (tid & 15) * 4;
    const int nf = (tid >> 4) * 4;

    float acc[8][8];
#pragma unroll
    for (int i = 0; i < 8; ++i)
#pragma unroll
        for (int j = 0; j < 8; ++j) acc[i][j] = 0.0f;

    for (int k0 = 0; k0 < D; k0 += 16) {
        const float4 av0 = *(const float4*)(x + (size_t)(m0 + r0) * D + k0 + kq0);
        const float4 av1 = *(const float4*)(x + (size_t)(m0 + r1) * D + k0 + kq1);
        const float4 pv0 = *(const float4*)(pb + k0 + kq0);
        const float4 pv1 = *(const float4*)(pb + k0 + kq1);
        const float4 bv0 = *(const float4*)(w + (size_t)(n0 + r0) * D + k0 + kq0);
        const float4 bv1 = *(const float4*)(w + (size_t)(n0 + r1) * D + k0 + kq1);
        As[kq0 + 0][r0] = av0.x - pv0.x;
        As[kq0 + 1][r0] = av0.y - pv0.y;
        As[kq0 + 2][r0] = av0.z - pv0.z;
        As[kq0 + 3][r0] = av0.w - pv0.w;
        As[kq1 + 0][r1] = av1.x - pv1.x;
        As[kq1 + 1][r1] = av1.y - pv1.y;
        As[kq1 + 2][r1] = av1.z - pv1.z;
        As[kq1 + 3][r1] = av1.w - pv1.w;
        Bs[kq0 + 0][r0] = bv0.x;
        Bs[kq0 + 1][r0] = bv0.y;
        Bs[kq0 + 2][r0] = bv0.z;
        Bs[kq0 + 3][r0] = bv0.w;
        Bs[kq1 + 0][r1] = bv1.x;
        Bs[kq1 + 1][r1] = bv1.y;
        Bs[kq1 + 2][r1] = bv1.z;
        Bs[kq1 + 3][r1] = bv1.w;
        __syncthreads();
#pragma unroll
        for (int kk = 0; kk < 16; ++kk) {
            const float4 A0 = *(const float4*)&As[kk][mf];
            const float4 A1 = *(const float4*)&As[kk][mf + 64];
            const float4 B0 = *(const float4*)&Bs[kk][nf];
            const float4 B1 = *(const float4*)&Bs[kk][nf + 64];
            const float a[8] = {A0.x, A0.y, A0.z, A0.w, A1.x, A1.y, A1.z, A1.w};
            const float b[8] = {B0.x, B0.y, B0.z, B0.w, B1.x, B1.y, B1.z, B1.w};
#pragma unroll
            for (int i = 0; i < 8; ++i)
#pragma unroll
                for (int j = 0; j < 8; ++j)
                    acc[i][j] = fmaf(a[i], b[j], acc[i][j]);
        }
        __syncthreads();
    }

#pragma unroll
    for (int i = 0; i < 8; ++i) {
        const int row = m0 + mf + (i & 3) + (i >> 2) * 64;
        const float4 v0 = make_float4(acc[i][0], acc[i][1], acc[i][2], acc[i][3]);
        const float4 v1 = make_float4(acc[i][4], acc[i][5], acc[i][6], acc[i][7]);
        *(float4*)(z + (size_t)row * HIDDEN + n0 + nf)      = v0;
        *(float4*)(z + (size_t)row * HIDDEN + n0 + nf + 64) = v1;
    }
}

__global__ __launch_bounds__(256, 2)
void topk_decode_fb(float* __restrict__ z,
                    const float* __restrict__ dA, const float* __restrict__ dB,
                    const float* __restrict__ po0, const float* __restrict__ po1,
                    float* __restrict__ rec0, float* __restrict__ rec1)
{
    __shared__ float    rowv[HIDDEN];
    __shared__ unsigned hist[4][257];
    __shared__ unsigned scanbuf[256];
    __shared__ float    selv[TOPK];
    __shared__ int      seli[TOPK];
    __shared__ unsigned sh_byte, sh_gt;

    const int tid = threadIdx.x;
    const size_t rowid = blockIdx.x;
    float* __restrict__ zrow = z + rowid * HIDDEN;

#pragma unroll
    for (int s = 0; s < 8; ++s) {
        const int i4 = s * 256 + tid;
        *(float4*)&rowv[i4 * 4] = *(const float4*)&zrow[i4 * 4];
    }
    __syncthreads();

    unsigned prefix = 0, prefmask = 0, need = TOPK;
#pragma unroll
    for (int p = 3; p >= 0; --p) {
        for (int i = tid; i < 4 * 257; i += 256) (&hist[0][0])[i] = 0;
        __syncthreads();
        const int sh = p * 8;
        for (int s = 0; s < 32; ++s) {
            const int i = s * 256 + tid;
            const unsigned k = fkey(rowv[i]);
            if ((k & prefmask) == prefix)
                atomicAdd(&hist[tid & 3][(k >> sh) & 255], 1);
        }
        __syncthreads();
        const unsigned tot = hist[0][tid] + hist[1][tid] + hist[2][tid] + hist[3][tid];
        hist[0][tid] = tot;
        __syncthreads();
        if (tid == 0) {
            unsigned cum = 0;
            int b = 255;
            for (;; --b) {
                const unsigned c = hist[0][b];
                if (cum + c >= need || b == 0) { sh_byte = (unsigned)b; sh_gt = cum; break; }
                cum += c;
            }
        }
        __syncthreads();
        prefix  |= sh_byte << sh;
        prefmask |= 0xFFu << sh;
        need -= sh_gt;
        __syncthreads();
    }
    const unsigned cut = prefix;
    const unsigned needEq = need;

    unsigned gtmask = 0, eqmask = 0;
#pragma unroll
    for (int j = 0; j < 32; ++j) {
        const int jr = (j + tid) & 31;
        const int i = tid * 32 + jr;
        const unsigned k = fkey(rowv[i]);
        if (k > cut)       gtmask |= 1u << jr;
        else if (k == cut) eqmask |= 1u << jr;
    }

    scanbuf[tid] = __popc(eqmask);
    __syncthreads();
    for (int off = 1; off < 256; off <<= 1) {
        const unsigned v = scanbuf[tid];
        const unsigned add = (tid >= off) ? scanbuf[tid - off] : 0u;
        __syncthreads();
        scanbuf[tid] = v + add;
        __syncthreads();
    }
    const unsigned eqexc = scanbuf[tid] - __popc(eqmask);
    __syncthreads();

    unsigned selmask = gtmask;
    {
        unsigned m = eqmask, r = eqexc;
        while (m) {
            const int j = __ffs(m) - 1;
            if (r < needEq) selmask |= 1u << j;
            ++r;
            m &= m - 1;
        }
    }

    scanbuf[tid] = __popc(selmask);
    __syncthreads();
    for (int off = 1; off < 256; off <<= 1) {
        const unsigned v = scanbuf[tid];
        const unsigned add = (tid >= off) ? scanbuf[tid - off] : 0u;
        __syncthreads();
        scanbuf[tid] = v + add;
        __syncthreads();
    }
    const unsigned selexc = scanbuf[tid] - __popc(selmask);

#pragma unroll
    for (int j = 0; j < 32; ++j) {
        const int jr = (j + tid) & 31;
        const int i = tid * 32 + jr;
        if ((selmask >> jr) & 1u) {
            const int slot = (int)(selexc + __popc(selmask & ((1u << jr) - 1u)));
            selv[slot] = rowv[i];
            seli[slot] = i;
        } else {
            rowv[i] = 0.0f;
        }
    }
    __syncthreads();

#pragma unroll
    for (int s = 0; s < 8; ++s) {
        const int i4 = s * 256 + tid;
        *(float4*)&zrow[i4 * 4] = *(float4*)&rowv[i4 * 4];
    }

    for (int d = tid; d < DIM0; d += 256) {
        float a = po0[d];
#pragma unroll
        for (int j = 0; j < TOPK; ++j)
            a = fmaf(selv[j], dA[(size_t)d * HIDDEN + seli[j]], a);
        rec0[rowid * DIM0 + d] = a;
    }
    for (int d = tid; d < DIM1; d += 256) {
        float a = po1[d];
#pragma unroll
        for (int j = 0; j < TOPK; ++j)
            a = fmaf(selv[j], dB[(size_t)d * HIDDEN + seli[j]], a);
        rec1[rowid * DIM1 + d] = a;
    }
}

// ===========================================================================
extern "C" void kernel_launch(void* const* d_in, const int* in_sizes, int n_in,
                              void* d_out, int out_size, void* d_ws, size_t ws_size,
                              hipStream_t stream)
{
    const float* x0  = (const float*)d_in[0];
    const float* x1  = (const float*)d_in[1];
    const float* pb0 = (const float*)d_in[2];
    const float* pb1 = (const float*)d_in[3];
    const float* ew0 = (const float*)d_in[4];
    const float* ew1 = (const float*)d_in[5];
    const float* dw0 = (const float*)d_in[6];
    const float* dw1 = (const float*)d_in[7];
    const float* po0 = (const float*)d_in[8];
    const float* po1 = (const float*)d_in[9];
    const int*  srcp = (const int*)d_in[10];

    float* z    = (float*)d_out;
    float* rec0 = z + (size_t)BATCH * HIDDEN;
    float* rec1 = rec0 + (size_t)BATCH * DIM0;

    // ws layout (bf16): xb[B][768] | wb[H][768] | dTb0[H][512] | dTb1[H][768]
    unsigned short* xb   = (unsigned short*)d_ws;
    unsigned short* wb   = xb   + (size_t)BATCH * DIM1;
    unsigned short* dTb0 = wb   + (size_t)HIDDEN * DIM1;
    unsigned short* dTb1 = dTb0 + (size_t)HIDDEN * DIM0;
    const size_t need = ((size_t)BATCH * DIM1 + (size_t)HIDDEN * DIM1 +
                         (size_t)HIDDEN * DIM0 + (size_t)HIDDEN * DIM1) * sizeof(unsigned short);

    if (ws_size >= need) {
        convert_xw<<<4096, 256, 0, stream>>>(x0, x1, pb0, pb1, ew0, ew1, srcp, xb, wb);
        dim3 tb(32, 8);
        transpose_dec_bf16<<<dim3(HIDDEN / 32, DIM0 / 32), tb, 0, stream>>>(dw0, dTb0, DIM0);
        transpose_dec_bf16<<<dim3(HIDDEN / 32, DIM1 / 32), tb, 0, stream>>>(dw1, dTb1, DIM1);
        gemm_bf16<<<(BATCH / 128) * (HIDDEN / 128), 256, 0, stream>>>(xb, wb, srcp, z);
        topk_rescore_decode<<<BATCH, 256, 0, stream>>>(
            z, x0, x1, pb0, pb1, ew0, ew1, dTb0, dTb1, po0, po1, rec0, rec1, srcp);
    } else {
        encode_gemm<<<dim3(HIDDEN / 128, BATCH / 128), 256, 0, stream>>>(
            x0, x1, pb0, pb1, ew0, ew1, srcp, z);
        topk_decode_fb<<<BATCH, 256, 0, stream>>>(z, dw0, dw1, po0, po1, rec0, rec1);
    }
}